// Round 1
// baseline (1340.511 us; speedup 1.0000x reference)
//
#include <hip/hip_runtime.h>
#include <math.h>

#define DIM    256
#define KCB    4096
#define NROWS  32768
#define DECAYF 0.99f

// dist kernel tiling
#define BM 128
#define BN 128
#define DK 16
#define TM 8
#define TN 8
#define KSPLIT 4
#define CPS (KCB / KSPLIT)   // 1024 codes per split

// ---- d_out offsets (in floats) ----
#define OUT_ZQ   0
#define OUT_IDX  8388608
#define OUT_LOSS 8421376
#define OUT_PPL  8421377
#define OUT_CB   8421378
#define OUT_CS   9469954
#define OUT_ES   9474050

// ---- d_ws offsets (in bytes) ----
#define WS_IDX    0          // N int32
#define WS_ZSQ    131072     // N float
#define WS_ESQ    262144     // K float
#define WS_BESTD  278528     // N*KSPLIT float
#define WS_BIDX   802816     // N*KSPLIT int32
#define WS_ZERO0  1327104    // start of zeroed region
#define WS_COUNTS 1327104    // K int32
#define WS_LOSS   1343488    // 1 float
#define WS_ENT    1343492    // 1 float
#define WS_EMBED  1343616    // K*DIM float (4 MB)
#define WS_ZEROLEN (1343616 + 4194304 - 1327104)

// per-wave sum of squares of a row of length DIM (used for z_sq and e_sq)
__global__ __launch_bounds__(256) void rowsq_kernel(
    const float* __restrict__ x, float* __restrict__ out, int nrows) {
  int gw = (blockIdx.x * 256 + threadIdx.x) >> 6;
  int lane = threadIdx.x & 63;
  if (gw >= nrows) return;
  float4 v = *(const float4*)(x + (size_t)gw * DIM + lane * 4);
  float s = v.x * v.x + v.y * v.y + v.z * v.z + v.w * v.w;
#pragma unroll
  for (int off = 32; off > 0; off >>= 1) s += __shfl_down(s, off);
  if (lane == 0) out[gw] = s;
}

// fp32 tiled distance + fused per-row argmin over this block's code split
__global__ __launch_bounds__(256, 2) void dist_kernel(
    const float* __restrict__ z, const float* __restrict__ cb,
    const float* __restrict__ e_sq, const float* __restrict__ z_sq,
    float* __restrict__ bestd, int* __restrict__ bidx_out) {
  __shared__ float zs[DK][BM + 4];
  __shared__ float es[DK][BN + 4];
  __shared__ float zsq_s[BM];
  __shared__ float rbest[BM][16];
  __shared__ int   ribx[BM][16];

  const int tid = threadIdx.x;
  const int tx = tid & 15;          // code dim
  const int ty = tid >> 4;          // row dim
  const int rb = blockIdx.x >> 2;
  const int split = blockIdx.x & (KSPLIT - 1);
  const int brow = rb * BM;
  const int c0 = split * CPS;

  if (tid < BM) zsq_s[tid] = z_sq[brow + tid];

  float best[TM];
  int   bidx[TM];
#pragma unroll
  for (int j = 0; j < TM; ++j) { best[j] = 1e30f; bidx[j] = 0; }

  for (int ct = 0; ct < CPS; ct += BN) {
    float acc[TM][TN];
#pragma unroll
    for (int j = 0; j < TM; ++j)
#pragma unroll
      for (int i = 0; i < TN; ++i) acc[j][i] = 0.f;

    for (int d0 = 0; d0 < DIM; d0 += DK) {
      __syncthreads();
#pragma unroll
      for (int p = 0; p < 8; ++p) {
        int r = p * 16 + ty;
        zs[tx][r] = z[(size_t)(brow + r) * DIM + d0 + tx];
        es[tx][r] = cb[(size_t)(c0 + ct + r) * DIM + d0 + tx];
      }
      __syncthreads();
#pragma unroll
      for (int d = 0; d < DK; ++d) {
        float zr[TM], er[TN];
#pragma unroll
        for (int j = 0; j < TM; ++j) zr[j] = zs[d][ty * TM + j];
#pragma unroll
        for (int i = 0; i < TN; ++i) er[i] = es[d][tx * TN + i];
#pragma unroll
        for (int j = 0; j < TM; ++j)
#pragma unroll
          for (int i = 0; i < TN; ++i) acc[j][i] += zr[j] * er[i];
      }
    }
    // combine: d = (z_sq + e_sq) - 2*dot  (2*acc is exact, one rounding like np)
#pragma unroll
    for (int i = 0; i < TN; ++i) {
      int c = c0 + ct + tx * TN + i;
      float e2 = e_sq[c];
#pragma unroll
      for (int j = 0; j < TM; ++j) {
        float s = zsq_s[ty * TM + j] + e2;
        float dv = s - 2.0f * acc[j][i];
        if (dv < best[j]) { best[j] = dv; bidx[j] = c; }
      }
    }
  }

  __syncthreads();
#pragma unroll
  for (int j = 0; j < TM; ++j) {
    rbest[ty * TM + j][tx] = best[j];
    ribx[ty * TM + j][tx]  = bidx[j];
  }
  __syncthreads();
  if (tid < BM) {
    float b = rbest[tid][0]; int bi = ribx[tid][0];
#pragma unroll
    for (int t = 1; t < 16; ++t) {
      float v = rbest[tid][t]; int vi = ribx[tid][t];
      if (v < b || (v == b && vi < bi)) { b = v; bi = vi; }
    }
    size_t o = (size_t)(brow + tid) * KSPLIT + split;
    bestd[o] = b;
    bidx_out[o] = bi;
  }
}

// merge the KSPLIT per-split minima; write final idx (int) + float indices out
__global__ __launch_bounds__(256) void merge_kernel(
    const float* __restrict__ bestd, const int* __restrict__ bidx,
    int* __restrict__ idx_out, float* __restrict__ out_idxf) {
  int n = blockIdx.x * 256 + threadIdx.x;
  if (n >= NROWS) return;
  float4 bv = *(const float4*)(bestd + (size_t)n * 4);
  int4   iv = *(const int4*)(bidx + (size_t)n * 4);
  float b = bv.x; int bi = iv.x;
  if (bv.y < b || (bv.y == b && iv.y < bi)) { b = bv.y; bi = iv.y; }
  if (bv.z < b || (bv.z == b && iv.z < bi)) { b = bv.z; bi = iv.z; }
  if (bv.w < b || (bv.w == b && iv.w < bi)) { b = bv.w; bi = iv.w; }
  idx_out[n] = bi;
  out_idxf[n] = (float)bi;
}

// one wave per row: gather z_q, straight-through output, loss partial,
// scatter EMA stats via atomics
__global__ __launch_bounds__(256) void gather_kernel(
    const float* __restrict__ z, const float* __restrict__ cb,
    const int* __restrict__ idx, float* __restrict__ out_zq,
    int* __restrict__ counts, float* __restrict__ embed_sum,
    float* __restrict__ loss_acc) {
  int gw = (blockIdx.x * 256 + threadIdx.x) >> 6;
  int lane = threadIdx.x & 63;
  if (gw >= NROWS) return;
  int k = idx[gw];
  float4 zq = *(const float4*)(cb + (size_t)k * DIM + lane * 4);
  float4 zv = *(const float4*)(z + (size_t)gw * DIM + lane * 4);
  // straight-through: z + (z_q - z), matching reference rounding
  float4 o;
  o.x = zv.x + (zq.x - zv.x);
  o.y = zv.y + (zq.y - zv.y);
  o.z = zv.z + (zq.z - zv.z);
  o.w = zv.w + (zq.w - zv.w);
  *(float4*)(out_zq + (size_t)gw * DIM + lane * 4) = o;
  float dx = zv.x - zq.x, dy = zv.y - zq.y, dz = zv.z - zq.z, dw = zv.w - zq.w;
  float s = dx * dx + dy * dy + dz * dz + dw * dw;
#pragma unroll
  for (int off = 32; off > 0; off >>= 1) s += __shfl_down(s, off);
  if (lane == 0) {
    atomicAdd(loss_acc, s);
    atomicAdd(&counts[k], 1);
  }
  size_t eo = (size_t)k * DIM + lane * 4;
  atomicAdd(&embed_sum[eo + 0], zv.x);
  atomicAdd(&embed_sum[eo + 1], zv.y);
  atomicAdd(&embed_sum[eo + 2], zv.z);
  atomicAdd(&embed_sum[eo + 3], zv.w);
}

// one wave per code: EMA updates + new codebook + entropy partial
__global__ __launch_bounds__(256) void finalize_codes(
    const float* __restrict__ ema_cs, const float* __restrict__ ema_es,
    const int* __restrict__ counts, const float* __restrict__ embed_sum,
    float* __restrict__ out_cb, float* __restrict__ out_cs,
    float* __restrict__ out_es, float* __restrict__ ent_acc) {
  int gw = (blockIdx.x * 256 + threadIdx.x) >> 6;
  int lane = threadIdx.x & 63;
  if (gw >= KCB) return;
  const float omd = 1.0f - DECAYF;
  float cnt = (float)counts[gw];
  float ncs = ema_cs[gw] * DECAYF + omd * cnt;
  float nden = ncs + 0.04096f;  // + EPS*K
  if (lane == 0) {
    out_cs[gw] = ncs;
    float p = cnt * (1.0f / (float)NROWS);
    atomicAdd(ent_acc, -p * logf(p + 1e-12f));
  }
  size_t o = (size_t)gw * DIM + lane * 4;
  float4 eb = *(const float4*)(embed_sum + o);
  float4 em = *(const float4*)(ema_es + o);
  float4 ne;
  ne.x = em.x * DECAYF + omd * eb.x;
  ne.y = em.y * DECAYF + omd * eb.y;
  ne.z = em.z * DECAYF + omd * eb.z;
  ne.w = em.w * DECAYF + omd * eb.w;
  // out_es / out_cb base offsets are only 8B-aligned -> use float2 stores
  float2 a0 = make_float2(ne.x, ne.y), a1 = make_float2(ne.z, ne.w);
  *(float2*)(out_es + o) = a0;
  *(float2*)(out_es + o + 2) = a1;
  float2 c0 = make_float2(ne.x / nden, ne.y / nden);
  float2 c1 = make_float2(ne.z / nden, ne.w / nden);
  *(float2*)(out_cb + o) = c0;
  *(float2*)(out_cb + o + 2) = c1;
}

__global__ void finalize_scalars(const float* __restrict__ loss_acc,
                                 const float* __restrict__ ent_acc,
                                 float* __restrict__ out_loss,
                                 float* __restrict__ out_ppl) {
  if (threadIdx.x == 0 && blockIdx.x == 0) {
    out_loss[0] = 0.25f * (loss_acc[0] / 8388608.0f);
    out_ppl[0] = expf(ent_acc[0]);
  }
}

extern "C" void kernel_launch(void* const* d_in, const int* in_sizes, int n_in,
                              void* d_out, int out_size, void* d_ws, size_t ws_size,
                              hipStream_t stream) {
  (void)in_sizes; (void)n_in; (void)out_size; (void)ws_size;
  const float* z      = (const float*)d_in[0];
  const float* cb     = (const float*)d_in[1];
  const float* ema_cs = (const float*)d_in[2];
  const float* ema_es = (const float*)d_in[3];
  float* out = (float*)d_out;
  char*  ws  = (char*)d_ws;

  int*   idx_i32 = (int*)(ws + WS_IDX);
  float* z_sq    = (float*)(ws + WS_ZSQ);
  float* e_sq    = (float*)(ws + WS_ESQ);
  float* bestd   = (float*)(ws + WS_BESTD);
  int*   bidx    = (int*)(ws + WS_BIDX);
  int*   counts  = (int*)(ws + WS_COUNTS);
  float* loss_p  = (float*)(ws + WS_LOSS);
  float* ent_p   = (float*)(ws + WS_ENT);
  float* embed   = (float*)(ws + WS_EMBED);

  hipMemsetAsync(ws + WS_ZERO0, 0, WS_ZEROLEN, stream);

  rowsq_kernel<<<NROWS / 4, 256, 0, stream>>>(z, z_sq, NROWS);
  rowsq_kernel<<<KCB / 4, 256, 0, stream>>>(cb, e_sq, KCB);

  dist_kernel<<<(NROWS / BM) * KSPLIT, 256, 0, stream>>>(z, cb, e_sq, z_sq,
                                                         bestd, bidx);
  merge_kernel<<<NROWS / 256, 256, 0, stream>>>(bestd, bidx, idx_i32,
                                                out + OUT_IDX);
  gather_kernel<<<NROWS / 4, 256, 0, stream>>>(z, cb, idx_i32, out + OUT_ZQ,
                                               counts, embed, loss_p);
  finalize_codes<<<KCB / 4, 256, 0, stream>>>(ema_cs, ema_es, counts, embed,
                                              out + OUT_CB, out + OUT_CS,
                                              out + OUT_ES, ent_p);
  finalize_scalars<<<1, 64, 0, stream>>>(loss_p, ent_p, out + OUT_LOSS,
                                         out + OUT_PPL);
}